// Round 14
// baseline (349.850 us; speedup 1.0000x reference)
//
#include <hip/hip_runtime.h>

typedef float f32x4  __attribute__((ext_vector_type(4)));
typedef float f32x16 __attribute__((ext_vector_type(16)));
typedef int   i32x4  __attribute__((ext_vector_type(4)));
typedef int   i32x8  __attribute__((ext_vector_type(8)));

#define AS1 __attribute__((address_space(1)))
#define AS3 __attribute__((address_space(3)))

// ---------------------------------------------------------------------------
// Kernel 1 (R1, proven): per-token quant of x -> fp8 e4m3 + scale
// ---------------------------------------------------------------------------
__global__ __launch_bounds__(256) void quant_x_fp8_kernel(
    const float* __restrict__ x, unsigned char* __restrict__ x8,
    float* __restrict__ xs, int K) {
  int m = blockIdx.x;
  int t = threadIdx.x;
  const f32x4* src = (const f32x4*)(x + (size_t)m * K + t * 16);
  f32x4 v[4];
  float am = 0.0f;
#pragma unroll
  for (int i = 0; i < 4; ++i) {
    v[i] = src[i];
#pragma unroll
    for (int j = 0; j < 4; ++j) am = fmaxf(am, __builtin_fabsf(v[i][j]));
  }
#pragma unroll
  for (int off = 32; off >= 1; off >>= 1)
    am = fmaxf(am, __shfl_xor(am, off, 64));
  __shared__ float red[4];
  int wv = t >> 6, lane = t & 63;
  if (lane == 0) red[wv] = am;
  __syncthreads();
  am = fmaxf(fmaxf(red[0], red[1]), fmaxf(red[2], red[3]));
  am = fmaxf(am, 1e-12f);
  float sc = am / 448.0f;
  if (t == 0) xs[m] = sc;
  i32x4 out;
#pragma unroll
  for (int i = 0; i < 4; ++i) {
    float q0 = v[i][0] / sc, q1 = v[i][1] / sc;
    float q2 = v[i][2] / sc, q3 = v[i][3] / sc;
    int p = __builtin_amdgcn_cvt_pk_fp8_f32(q0, q1, 0, false);
    p = __builtin_amdgcn_cvt_pk_fp8_f32(q2, q3, p, true);
    out[i] = p;
  }
  *(i32x4*)(x8 + (size_t)m * K + t * 16) = out;
}

// ---------------------------------------------------------------------------
// Kernel 2 (R1, proven): weight f32 (fp8-representable) -> fp8 bytes
// ---------------------------------------------------------------------------
__global__ __launch_bounds__(256) void quant_w_fp8_kernel(
    const float* __restrict__ w, unsigned char* __restrict__ w8) {
  size_t idx = (size_t)blockIdx.x * 256 + threadIdx.x;
  const f32x4* src = (const f32x4*)w + idx * 4;
  i32x4 out;
#pragma unroll
  for (int i = 0; i < 4; ++i) {
    f32x4 v = src[i];
    int p = __builtin_amdgcn_cvt_pk_fp8_f32(v[0], v[1], 0, false);
    p = __builtin_amdgcn_cvt_pk_fp8_f32(v[2], v[3], p, true);
    out[i] = p;
  }
  ((i32x4*)w8)[idx] = out;
}

// ---------------------------------------------------------------------------
// Kernel 3: MX-fp8 GEMM. R26 = R23 frame + B direct-from-global (L2) into
// register double-buffer; A-only LDS (32KB).
// R25 post-mortem: 73728-LDS did not co-reside (granularity rounds up?) and
// K-64 bodies doubled barrier overhead: 252us. Resource model settled by
// R23/R24/R25: the LDS DATA PORT is per-CU and shared -- R23's co-resident
// blocks were a null because both competed for a ~73%-busy port (per CU
// body: 96KB traffic ~1130cy vs 1547 measured). Co-residency cannot create
// LDS bandwidth; geometries that cut LDS/FLOP lost more TLP than saved.
// R26 removes B from LDS: the MFMA B-fragment is 32B/lane at computable
// global addresses (row = n0+wc*64+nj*32+l31, bytes t*128+ks*64+hi2*32 --
// verified identical to the validated LDS-path fragment bytes). B panels
// have strong cross-block L2 reuse (shared by all M-blocks in a column;
// XCD swizzle). Per block-body LDS: 96KB -> 48KB (A reads 32KB + writes
// 16KB) => per-CU LDS ~430cy/body; B via L2 at 49B/cy << 134B/cy ceiling;
// MFMA (~550cy/body/CU at 2 blocks) becomes the binding pipe, and
// co-residency (trivially achieved at 32KB LDS) keeps it fed.
// Frame (R23-proven): 128x128 tile, 256 thr, 4 waves 2(wr)x2(wc), wave
// 64x64, acc[2][2] f32x16; ratio-fold (R20-validated); A swizzle + linear
// stage (validated); 1 barrier/body; stage A(T+1) into buf of T-1 (WAR rule
// R17/R23); vmcnt(0) at body close covers A-stage and B-prefetch (both
// have full-body cover). B regs double-buffered bfE/bfO, static indexing
// (rule #20) via 2-body unrolled loop. launch_bounds(256,2): cap 256,
// demand ~180.
// Tripwires: LDS_Block 32768; WRITE == 131072KB (else spill); VGPR 170-190;
// Occupancy ~21-25 (2 blocks/CU).
// ---------------------------------------------------------------------------
__global__ __launch_bounds__(256, 2) void gemm_mxfp8_kernel(
    const unsigned char* __restrict__ A8,   // [M][K] fp8
    const unsigned char* __restrict__ W8,   // [N][K] fp8
    const float* __restrict__ xs,           // [M]
    const float* __restrict__ wsinv,        // [N/128][K/128]
    float* __restrict__ Y,                  // [M][N] f32
    int M, int N, int K) {
  const int KB = K >> 7;  // K/128 tiles (32), even

  int bid = blockIdx.x, nwg = gridDim.x;
  int wg = (bid & 7) * (nwg >> 3) + (bid >> 3);
  int mt = M >> 7;                  // 32
  int bm = wg & (mt - 1);
  int bn = wg / mt;                 // 0..63
  int m0 = bm << 7, n0 = bn << 7;   // 128 x 128 tile

  __shared__ __align__(16) char lds[32768];  // A buf0 @0, buf1 @16384

  const int tid = threadIdx.x, wv = tid >> 6, lane = tid & 63;
  const int wr = wv >> 1, wc = wv & 1;          // 2 x 2 wave grid
  const int l31 = lane & 31, hi2 = lane >> 5;
  const int salt = l31 & 7;

  // per-lane A slot offsets (validated swizzle)
  const int sL0 = ((hi2 * 2 + 0) ^ salt) << 4;       // ks=0, k-low 16B
  const int sH0 = ((hi2 * 2 + 1) ^ salt) << 4;       // ks=0, k-high
  const int sL1 = ((4 + hi2 * 2 + 0) ^ salt) << 4;   // ks=1
  const int sH1 = ((4 + hi2 * 2 + 1) ^ salt) << 4;

  const int aRow = (wr * 64 + l31) * 128;   // A row within 128-row panel
  const int aL0 = aRow + sL0, aH0 = aRow + sH0;
  const int aL1 = aRow + sL1, aH1 = aRow + sH1;

  // A staging: 128-row panel (16KB) in 4 sweeps of 32 rows (256thr x 16B);
  // dest = buf + sweep*4096 + tid*16 (linear); src row = sweep*32+(tid>>3);
  // col pre-swizzled (involution).
  const int stgD = tid << 4;
  const int rIdx = tid >> 3;                 // 0..31
  const int cSrc = ((tid & 7) ^ (rIdx & 7)) << 4;
  const size_t rowB = (size_t)K;  // fp8: 1 byte/elem
  const size_t g32 = 32 * rowB;
  const char* pA = (const char*)A8 + (size_t)(m0 + rIdx) * rowB + cSrc;

  // B direct-from-global per-lane bases (nj = 0, 1), tile 0:
  // row = n0 + wc*64 + nj*32 + l31; byte = hi2*32 (+{0,16,64,80} per frag)
  const char* pB0 = (const char*)W8 + (size_t)(n0 + wc * 64 + l31) * rowB +
                    hi2 * 32;
  const char* pB1 = pB0 + 32 * rowB;

  const float* wsv = wsinv + (size_t)bn * KB;  // one scale row per 128 cols

  f32x16 acc[2][2];
#pragma unroll
  for (int i = 0; i < 2; ++i)
#pragma unroll
    for (int j = 0; j < 2; ++j) acc[i][j] = (f32x16)0.0f;

  i32x8 af[2], bfE[2][2], bfO[2][2];

#define GL(SRC, DST)                                                           \
  __builtin_amdgcn_global_load_lds((const AS1 void*)(SRC), (AS3 void*)(DST),   \
                                   16, 0, 0)
// A panel (128 rows, 16KB): 4 gloads (32-row sweeps)
#define STG_A(COND, SB, SRC)                                                   \
  if (COND) {                                                                  \
    const char* s_ = (SRC);                                                    \
    char* d_ = lds + (SB) + stgD;                                              \
    GL(s_, d_);                                                                \
    GL(s_ + g32, d_ + 4096);                                                   \
    GL(s_ + 2 * g32, d_ + 8192);                                               \
    GL(s_ + 3 * g32, d_ + 12288);                                              \
  }

// A frags for one mj (both ksteps), literal buf base RB: 4 ds_read_b128
#define RD_A(RB, MJ)                                                           \
  {                                                                            \
    const char* p_ = lds + (RB) + (MJ) * 4096;                                 \
    i32x4 lo0 = *(const i32x4*)(p_ + aL0);                                     \
    i32x4 hi0 = *(const i32x4*)(p_ + aH0);                                     \
    i32x4 lo1 = *(const i32x4*)(p_ + aL1);                                     \
    i32x4 hi1 = *(const i32x4*)(p_ + aH1);                                     \
    af[0] = __builtin_shufflevector(lo0, hi0, 0, 1, 2, 3, 4, 5, 6, 7);         \
    af[1] = __builtin_shufflevector(lo1, hi1, 0, 1, 2, 3, 4, 5, 6, 7);         \
  }

// B frags (nj 0..1 x ks 0..1) direct from global: 8 global_load_dwordx4.
// Fragment bytes verified == validated LDS-path bytes:
// lane reads row (n0+wc*64+nj*32+l31), bytes t*128 + {hi2*32, +16,
// 64+hi2*32, +16}.
#define LDB(COND, DST)                                                         \
  if (COND) {                                                                  \
    i32x4 l0 = *(const i32x4*)(pB0);                                           \
    i32x4 h0 = *(const i32x4*)(pB0 + 16);                                      \
    i32x4 l1 = *(const i32x4*)(pB0 + 64);                                      \
    i32x4 h1 = *(const i32x4*)(pB0 + 80);                                      \
    DST[0][0] = __builtin_shufflevector(l0, h0, 0, 1, 2, 3, 4, 5, 6, 7);       \
    DST[0][1] = __builtin_shufflevector(l1, h1, 0, 1, 2, 3, 4, 5, 6, 7);       \
    l0 = *(const i32x4*)(pB1);                                                 \
    h0 = *(const i32x4*)(pB1 + 16);                                            \
    l1 = *(const i32x4*)(pB1 + 64);                                            \
    h1 = *(const i32x4*)(pB1 + 80);                                            \
    DST[1][0] = __builtin_shufflevector(l0, h0, 0, 1, 2, 3, 4, 5, 6, 7);       \
    DST[1][1] = __builtin_shufflevector(l1, h1, 0, 1, 2, 3, 4, 5, 6, 7);       \
  }

// ratio-fold + chained MFMA pair for one (mj,nj) using frag set BF
#define MMFn(MJ, NJ, R_, BF)                                                   \
  {                                                                            \
    _Pragma("unroll") for (int q = 0; q < 16; ++q)                             \
        acc[MJ][NJ][q] *= (R_);                                                \
    acc[MJ][NJ] = __builtin_amdgcn_mfma_scale_f32_32x32x64_f8f6f4(             \
        af[0], BF[NJ][0], acc[MJ][NJ], 0, 0, 0, 0x7f7f7f7f, 0, 0x7f7f7f7f);    \
    acc[MJ][NJ] = __builtin_amdgcn_mfma_scale_f32_32x32x64_f8f6f4(             \
        af[1], BF[NJ][1], acc[MJ][NJ], 0, 0, 0, 0x7f7f7f7f, 0, 0x7f7f7f7f);    \
  }

  // prologue: stage A(0)->buf0; load B(0)->bfE; advance B ptrs to tile 1;
  // drain; publish.
  STG_A(true, 0, pA);
  LDB(true, bfE);
  pB0 += 128;
  pB1 += 128;
  asm volatile("s_waitcnt vmcnt(0)" ::: "memory");
  __builtin_amdgcn_s_barrier();

  const char* pAs = pA + 128;  // A stage source col of tile T+1
  float sp_ = wsv[0];          // previous-tile scale (ratio = 1 at t = 0)

// body T: prefetch B(T+1)->BFN; stage A(T+1)->SB (buf of T-1, WAR-safe);
// read A(T) from RB; MFMA with fold using BFC; vmcnt(0)+barrier close.
#define TILE(T, RB, SB, G, BFC, BFN)                                           \
  {                                                                            \
    float sc_ = wsv[(T)];                                                      \
    float r_ = sp_ / sc_;                                                      \
    sp_ = sc_;                                                                 \
    LDB(G, BFN);                                                               \
    STG_A(G, (SB), pAs);                                                       \
    RD_A(RB, 0);                                                               \
    __builtin_amdgcn_s_setprio(1);                                             \
    MMFn(0, 0, r_, BFC);                                                       \
    MMFn(0, 1, r_, BFC);                                                       \
    __builtin_amdgcn_s_setprio(0);                                             \
    RD_A(RB, 1);                                                               \
    __builtin_amdgcn_s_setprio(1);                                             \
    MMFn(1, 0, r_, BFC);                                                       \
    MMFn(1, 1, r_, BFC);                                                       \
    __builtin_amdgcn_s_setprio(0);                                             \
    asm volatile("s_waitcnt vmcnt(0)" ::: "memory");                           \
    __builtin_amdgcn_s_barrier();                                              \
    pAs += 128;                                                                \
    pB0 += 128;                                                                \
    pB1 += 128;                                                                \
  }

#pragma unroll 1
  for (int t = 0; t < KB; t += 2) {
    TILE(t, 0, 16384, true, bfE, bfO)
    TILE(t + 1, 16384, 0, (t + 2) < KB, bfO, bfE)
  }

#undef TILE
#undef MMFn
#undef LDB
#undef RD_A
#undef STG_A
#undef GL

  // epilogue (validated C/D mapping): col=l31, row=q*8+hi2*4+j.
  // acc is in s_last domain: Y = acc * s_last * xs[row].
  const float sl_ = sp_;
#pragma unroll
  for (int mj = 0; mj < 2; ++mj)
#pragma unroll
    for (int nj = 0; nj < 2; ++nj) {
      int col = n0 + wc * 64 + nj * 32 + l31;
#pragma unroll
      for (int q = 0; q < 4; ++q) {
        int row0 = m0 + wr * 64 + mj * 32 + q * 8 + hi2 * 4;
        f32x4 sv = *(const f32x4*)(xs + row0);
#pragma unroll
        for (int j = 0; j < 4; ++j)
          Y[(size_t)(row0 + j) * N + col] = acc[mj][nj][q * 4 + j] * sv[j] * sl_;
      }
    }
}

// ---------------------------------------------------------------------------
extern "C" void kernel_launch(void* const* d_in, const int* in_sizes, int n_in,
                              void* d_out, int out_size, void* d_ws, size_t ws_size,
                              hipStream_t stream) {
  const float* x     = (const float*)d_in[0];   // [B,S,K] f32
  const float* w     = (const float*)d_in[1];   // [N,K] f32 (fp8-representable)
  const float* wsinv = (const float*)d_in[2];   // [N/128,K/128] f32
  float* y = (float*)d_out;

  const int K = 4096;
  const int M = in_sizes[0] / K;   // 4096
  const int N = in_sizes[1] / K;   // 8192

  unsigned char* x8 = (unsigned char*)d_ws;                       // M*K
  float* xs = (float*)((char*)d_ws + (size_t)M * K);              // M floats
  unsigned char* w8 =
      (unsigned char*)d_ws + (size_t)M * K + (size_t)M * 4;       // N*K

  quant_x_fp8_kernel<<<M, 256, 0, stream>>>(x, x8, xs, K);
  quant_w_fp8_kernel<<<(int)(((size_t)N * K / 16 + 255) / 256), 256, 0,
                       stream>>>(w, w8);

  dim3 grid((M / 128) * (N / 128));  // 2048
  gemm_mxfp8_kernel<<<grid, 256, 0, stream>>>(x8, w8, xs, wsinv, y, M, N, K);
}

// Round 15
// 217.711 us; speedup vs baseline: 1.6069x; 1.6069x over previous
//
#include <hip/hip_runtime.h>

typedef float f32x4  __attribute__((ext_vector_type(4)));
typedef float f32x16 __attribute__((ext_vector_type(16)));
typedef int   i32x4  __attribute__((ext_vector_type(4)));
typedef int   i32x8  __attribute__((ext_vector_type(8)));

#define AS1 __attribute__((address_space(1)))
#define AS3 __attribute__((address_space(3)))

// ---------------------------------------------------------------------------
// Kernel 1 (R1, proven): per-token quant of x -> fp8 e4m3 + scale
// ---------------------------------------------------------------------------
__global__ __launch_bounds__(256) void quant_x_fp8_kernel(
    const float* __restrict__ x, unsigned char* __restrict__ x8,
    float* __restrict__ xs, int K) {
  int m = blockIdx.x;
  int t = threadIdx.x;
  const f32x4* src = (const f32x4*)(x + (size_t)m * K + t * 16);
  f32x4 v[4];
  float am = 0.0f;
#pragma unroll
  for (int i = 0; i < 4; ++i) {
    v[i] = src[i];
#pragma unroll
    for (int j = 0; j < 4; ++j) am = fmaxf(am, __builtin_fabsf(v[i][j]));
  }
#pragma unroll
  for (int off = 32; off >= 1; off >>= 1)
    am = fmaxf(am, __shfl_xor(am, off, 64));
  __shared__ float red[4];
  int wv = t >> 6, lane = t & 63;
  if (lane == 0) red[wv] = am;
  __syncthreads();
  am = fmaxf(fmaxf(red[0], red[1]), fmaxf(red[2], red[3]));
  am = fmaxf(am, 1e-12f);
  float sc = am / 448.0f;
  if (t == 0) xs[m] = sc;
  i32x4 out;
#pragma unroll
  for (int i = 0; i < 4; ++i) {
    float q0 = v[i][0] / sc, q1 = v[i][1] / sc;
    float q2 = v[i][2] / sc, q3 = v[i][3] / sc;
    int p = __builtin_amdgcn_cvt_pk_fp8_f32(q0, q1, 0, false);
    p = __builtin_amdgcn_cvt_pk_fp8_f32(q2, q3, p, true);
    out[i] = p;
  }
  *(i32x4*)(x8 + (size_t)m * K + t * 16) = out;
}

// ---------------------------------------------------------------------------
// Kernel 2 (R1, proven): weight f32 (fp8-representable) -> fp8 bytes
// ---------------------------------------------------------------------------
__global__ __launch_bounds__(256) void quant_w_fp8_kernel(
    const float* __restrict__ w, unsigned char* __restrict__ w8) {
  size_t idx = (size_t)blockIdx.x * 256 + threadIdx.x;
  const f32x4* src = (const f32x4*)w + idx * 4;
  i32x4 out;
#pragma unroll
  for (int i = 0; i < 4; ++i) {
    f32x4 v = src[i];
    int p = __builtin_amdgcn_cvt_pk_fp8_f32(v[0], v[1], 0, false);
    p = __builtin_amdgcn_cvt_pk_fp8_f32(v[2], v[3], p, true);
    out[i] = p;
  }
  ((i32x4*)w8)[idx] = out;
}

// ---------------------------------------------------------------------------
// Kernel 3: MX-fp8 GEMM. R27 = 128x64 wave tile (low LDS/FLOP) x 2
// co-resident blocks via 2x24KB K-64 buffers.
// R26 post-mortem: B-direct-from-global = 64 cache lines per load (each
// lane a different row) -> FETCH 517MB, 316us. B must stage through LDS.
// Settled model (R20/R23/R24/R25): per-CU LDS port is THE binding
// resource. Per 8.4 MFLOP: 64x64 wave tiles = 256 b128 reads (~2050cy+)
// vs MFMA 1100cy; 128x64 wave tiles = 192 reads + writes ~= 1920cy
// (~102us GEMM floor). R24 ran 128x64 with 1 wave/SIMD (no TLP, 240us);
// R25's 73728 LDS missed the co-residency threshold (proven: 65536 yes
// (R23), 73728 no, 81920 no).
// R27: 256 thr, 4 waves 2(wr)x2(wc), wave 128x64, block 256x128, K-64
// bodies; LDS = 2 bufs x 24576 {A 16KB, B 8KB} = 49152 -> 2 blocks/CU
// guaranteed (2x49152 = 98304 << 131072-proven). Static even/odd bodies:
// body 2t reads buf0/stages buf1, body 2t+1 reads buf1/stages buf0 (no
// rotating registers). Stage T+1 at body TOP -> full-body cover;
// vmcnt(0) + 1 barrier per body; the per-body drain anti-phases across
// the two independent blocks (the co-residency mechanism R23 proved).
// WAR: stage(b+1) -> buf((b+1)&1) = buf of body b-1, whose reads ended
// before barrier(b-1), one barrier before this stage issues (R17 rule).
// All machinery validated: R25's K-64 layout/swizzle/staging/anchors
// (absmax 0.0625), R24's 128x64 epilogue mapping, R20's ratio-fold
// (even bodies fold acc *= s_prev/s_cur; odd bodies direct-chain).
// launch_bounds(256,2): VGPR cap 256 >= R25's measured 164.
// Tripwires: Occupancy ~25 (11 => no co-residency); LDS_Block 49152;
// WRITE == 131072KB (else spill); VGPR 160-190.
// ---------------------------------------------------------------------------
__global__ __launch_bounds__(256, 2) void gemm_mxfp8_kernel(
    const unsigned char* __restrict__ A8,   // [M][K] fp8
    const unsigned char* __restrict__ W8,   // [N][K] fp8
    const float* __restrict__ xs,           // [M]
    const float* __restrict__ wsinv,        // [N/128][K/128]
    float* __restrict__ Y,                  // [M][N] f32
    int M, int N, int K) {
  const int KB = K >> 7;  // K/128 scale tiles (32); bodies = 2*KB

  int bid = blockIdx.x, nwg = gridDim.x;
  int wg = (bid & 7) * (nwg >> 3) + (bid >> 3);
  int mt = M >> 8;                  // 16
  int bm = wg & (mt - 1);
  int bn = wg / mt;                 // 0..63
  int m0 = bm << 8, n0 = bn << 7;   // 256 x 128 tile

  __shared__ __align__(16) char lds[49152];  // buf0 @0, buf1 @24576

  const int tid = threadIdx.x, wv = tid >> 6, lane = tid & 63;
  const int wr = wv >> 1, wc = wv & 1;          // 2 x 2 wave grid
  const int l31 = lane & 31, hi2 = lane >> 5;

  // read anchors for the K-64 interleaved layout (R25-validated):
  // anchor(s) = (l31>>1)*128 + ((((l31&1)<<2)|s) ^ ((l31>>1)&7))*16
  const int lineB = (l31 >> 1) * 128;
  const int par4 = (l31 & 1) << 2;
  const int xr = (l31 >> 1) & 7;
  const int s0 = 2 * hi2, s1 = 2 * hi2 + 1;
  const int aL = wr * 8192 + lineB + ((par4 | s0) ^ xr) * 16;
  const int aH = wr * 8192 + lineB + ((par4 | s1) ^ xr) * 16;
  const int bL = wc * 4096 + lineB + ((par4 | s0) ^ xr) * 16;
  const int bH = wc * 4096 + lineB + ((par4 | s1) ^ xr) * 16;

  // staging (R25-validated): dest = region + sweep*4096 + tid*16 (linear);
  // src row = 64*sweep + 2*(tid>>3) + (inv>>2), col = (inv&3)*16.
  const int stgD = tid << 4;
  const int inv = (tid & 7) ^ ((tid >> 3) & 7);
  const int rLoc = 2 * (tid >> 3) + (inv >> 2);
  const int cSrc = (inv & 3) << 4;
  const size_t rowB = (size_t)K;  // fp8: 1 byte/elem
  const size_t g64r = 64 * rowB;  // 64-row sweep stride
  const char* pA = (const char*)A8 + (size_t)(m0 + rLoc) * rowB + cSrc;
  const char* pB = (const char*)W8 + (size_t)(n0 + rLoc) * rowB + cSrc;

  const float* wsv = wsinv + (size_t)bn * KB;  // N-tile 128 = one scale row

  f32x16 acc[4][2];
#pragma unroll
  for (int i = 0; i < 4; ++i)
#pragma unroll
    for (int j = 0; j < 2; ++j) acc[i][j] = (f32x16)0.0f;

  i32x8 af, bf[2];

#define GL(SRC, DST)                                                           \
  __builtin_amdgcn_global_load_lds((const AS1 void*)(SRC), (AS3 void*)(DST),   \
                                   16, 0, 0)
// A panel (256 rows x 64B = 16KB): 4 sweeps
#define STG_A(COND, SB, SRC)                                                   \
  if (COND) {                                                                  \
    const char* s_ = (SRC);                                                    \
    char* d_ = lds + (SB) + stgD;                                              \
    GL(s_, d_);                                                                \
    GL(s_ + g64r, d_ + 4096);                                                  \
    GL(s_ + 2 * g64r, d_ + 8192);                                              \
    GL(s_ + 3 * g64r, d_ + 12288);                                             \
  }
// B panel (128 rows x 64B = 8KB) at region +16384: 2 sweeps
#define STG_B(COND, SB, SRC)                                                   \
  if (COND) {                                                                  \
    const char* s_ = (SRC);                                                    \
    char* d_ = lds + (SB) + 16384 + stgD;                                      \
    GL(s_, d_);                                                                \
    GL(s_ + g64r, d_ + 4096);                                                  \
  }

// A frag for one mj (K-64), literal buf base RB: 2 ds_read_b128 -> af
#define RD_A(RB, MJ)                                                           \
  {                                                                            \
    const char* p_ = lds + (RB) + (MJ) * 2048;                                 \
    i32x4 lo = *(const i32x4*)(p_ + aL);                                       \
    i32x4 hi = *(const i32x4*)(p_ + aH);                                       \
    af = __builtin_shufflevector(lo, hi, 0, 1, 2, 3, 4, 5, 6, 7);              \
  }
// B frag for one nj (K-64), literal buf base RB (B at +16384)
#define RD_B(RB, NJ)                                                           \
  {                                                                            \
    const char* p_ = lds + (RB) + 16384 + (NJ) * 2048;                         \
    i32x4 lo = *(const i32x4*)(p_ + bL);                                       \
    i32x4 hi = *(const i32x4*)(p_ + bH);                                       \
    bf[NJ] = __builtin_shufflevector(lo, hi, 0, 1, 2, 3, 4, 5, 6, 7);          \
  }

// fold + MFMA (even bodies): acc = mfma(af, bf, acc*r)
#define MMFF(MJ, NJ, R_)                                                       \
  {                                                                            \
    _Pragma("unroll") for (int q = 0; q < 16; ++q)                             \
        acc[MJ][NJ][q] *= (R_);                                                \
    acc[MJ][NJ] = __builtin_amdgcn_mfma_scale_f32_32x32x64_f8f6f4(             \
        af, bf[NJ], acc[MJ][NJ], 0, 0, 0, 0x7f7f7f7f, 0, 0x7f7f7f7f);          \
  }
// direct MFMA (odd bodies): acc = mfma(af, bf, acc)
#define MMFD(MJ, NJ)                                                           \
  acc[MJ][NJ] = __builtin_amdgcn_mfma_scale_f32_32x32x64_f8f6f4(               \
      af, bf[NJ], acc[MJ][NJ], 0, 0, 0, 0x7f7f7f7f, 0, 0x7f7f7f7f);

// body: read body b from RD, stage body b+1 -> ST (issued at top, full-body
// cover), MFMA, vmcnt(0)+barrier close.
#define BODY_CORE(MM0, MM1, MM2, MM3, RD, ST, G)                               \
  {                                                                            \
    RD_B(RD, 0);                                                               \
    RD_B(RD, 1);                                                               \
    RD_A(RD, 0);                                                               \
    STG_A(G, ST, pAs);                                                         \
    __builtin_amdgcn_s_setprio(1);                                             \
    MM0;                                                                       \
    __builtin_amdgcn_s_setprio(0);                                             \
    STG_B(G, ST, pBs);                                                         \
    RD_A(RD, 1);                                                               \
    __builtin_amdgcn_s_setprio(1);                                             \
    MM1;                                                                       \
    __builtin_amdgcn_s_setprio(0);                                             \
    RD_A(RD, 2);                                                               \
    __builtin_amdgcn_s_setprio(1);                                             \
    MM2;                                                                       \
    __builtin_amdgcn_s_setprio(0);                                             \
    RD_A(RD, 3);                                                               \
    __builtin_amdgcn_s_setprio(1);                                             \
    MM3;                                                                       \
    __builtin_amdgcn_s_setprio(0);                                             \
    asm volatile("s_waitcnt vmcnt(0)" ::: "memory");                           \
    __builtin_amdgcn_s_barrier();                                              \
    pAs += 64;                                                                 \
    pBs += 64;                                                                 \
  }

#define BODY_E(T, G)                                                           \
  {                                                                            \
    float sc_ = wsv[(T)];                                                      \
    float r_ = sp_ / sc_;                                                      \
    sp_ = sc_;                                                                 \
    BODY_CORE(MMFF(0, 0, r_); MMFF(0, 1, r_), MMFF(1, 0, r_); MMFF(1, 1, r_),  \
              MMFF(2, 0, r_); MMFF(2, 1, r_), MMFF(3, 0, r_); MMFF(3, 1, r_),  \
              0, 24576, G)                                                     \
  }
#define BODY_O(G)                                                              \
  BODY_CORE(MMFD(0, 0); MMFD(0, 1), MMFD(1, 0); MMFD(1, 1),                    \
            MMFD(2, 0); MMFD(2, 1), MMFD(3, 0); MMFD(3, 1), 24576, 0, G)

  // prologue: stage body0 -> buf0 (6 gloads); drain; publish.
  STG_A(true, 0, pA);
  STG_B(true, 0, pB);
  asm volatile("s_waitcnt vmcnt(0)" ::: "memory");
  __builtin_amdgcn_s_barrier();

  const char* pAs = pA + 64;   // stage source K-offset of body 1
  const char* pBs = pB + 64;
  float sp_ = wsv[0];          // previous-tile scale (ratio = 1 at t = 0)

#pragma unroll 1
  for (int t = 0; t < KB; ++t) {
    BODY_E(t, true)           // body 2t: reads buf0, stages body 2t+1
    BODY_O(t < KB - 1)        // body 2t+1: reads buf1, stages body 2t+2
  }

#undef BODY_O
#undef BODY_E
#undef BODY_CORE
#undef MMFD
#undef MMFF
#undef RD_B
#undef RD_A
#undef STG_B
#undef STG_A
#undef GL

  // epilogue (R24/R25-proven mapping, wave 128x64): col=l31, row=q*8+hi2*4+j.
  // acc is in s_last domain: Y = acc * s_last * xs[row].
  const float sl_ = sp_;
#pragma unroll
  for (int mj = 0; mj < 4; ++mj)
#pragma unroll
    for (int nj = 0; nj < 2; ++nj) {
      int col = n0 + wc * 64 + nj * 32 + l31;
#pragma unroll
      for (int q = 0; q < 4; ++q) {
        int row0 = m0 + wr * 128 + mj * 32 + q * 8 + hi2 * 4;
        f32x4 sv = *(const f32x4*)(xs + row0);
#pragma unroll
        for (int j = 0; j < 4; ++j)
          Y[(size_t)(row0 + j) * N + col] = acc[mj][nj][q * 4 + j] * sv[j] * sl_;
      }
    }
}

// ---------------------------------------------------------------------------
extern "C" void kernel_launch(void* const* d_in, const int* in_sizes, int n_in,
                              void* d_out, int out_size, void* d_ws, size_t ws_size,
                              hipStream_t stream) {
  const float* x     = (const float*)d_in[0];   // [B,S,K] f32
  const float* w     = (const float*)d_in[1];   // [N,K] f32 (fp8-representable)
  const float* wsinv = (const float*)d_in[2];   // [N/128,K/128] f32
  float* y = (float*)d_out;

  const int K = 4096;
  const int M = in_sizes[0] / K;   // 4096
  const int N = in_sizes[1] / K;   // 8192

  unsigned char* x8 = (unsigned char*)d_ws;                       // M*K
  float* xs = (float*)((char*)d_ws + (size_t)M * K);              // M floats
  unsigned char* w8 =
      (unsigned char*)d_ws + (size_t)M * K + (size_t)M * 4;       // N*K

  quant_x_fp8_kernel<<<M, 256, 0, stream>>>(x, x8, xs, K);
  quant_w_fp8_kernel<<<(int)(((size_t)N * K / 16 + 255) / 256), 256, 0,
                       stream>>>(w, w8);

  dim3 grid((M / 256) * (N / 128));  // 1024
  gemm_mxfp8_kernel<<<grid, 256, 0, stream>>>(x8, w8, xs, wsinv, y, M, N, K);
}

// Round 16
// 211.484 us; speedup vs baseline: 1.6543x; 1.0294x over previous
//
#include <hip/hip_runtime.h>

typedef float f32x4  __attribute__((ext_vector_type(4)));
typedef float f32x16 __attribute__((ext_vector_type(16)));
typedef int   i32x4  __attribute__((ext_vector_type(4)));
typedef int   i32x8  __attribute__((ext_vector_type(8)));

#define AS1 __attribute__((address_space(1)))
#define AS3 __attribute__((address_space(3)))

// ---------------------------------------------------------------------------
// Kernel 1 (R1, proven): per-token quant of x -> fp8 e4m3 + scale
// ---------------------------------------------------------------------------
__global__ __launch_bounds__(256) void quant_x_fp8_kernel(
    const float* __restrict__ x, unsigned char* __restrict__ x8,
    float* __restrict__ xs, int K) {
  int m = blockIdx.x;
  int t = threadIdx.x;
  const f32x4* src = (const f32x4*)(x + (size_t)m * K + t * 16);
  f32x4 v[4];
  float am = 0.0f;
#pragma unroll
  for (int i = 0; i < 4; ++i) {
    v[i] = src[i];
#pragma unroll
    for (int j = 0; j < 4; ++j) am = fmaxf(am, __builtin_fabsf(v[i][j]));
  }
#pragma unroll
  for (int off = 32; off >= 1; off >>= 1)
    am = fmaxf(am, __shfl_xor(am, off, 64));
  __shared__ float red[4];
  int wv = t >> 6, lane = t & 63;
  if (lane == 0) red[wv] = am;
  __syncthreads();
  am = fmaxf(fmaxf(red[0], red[1]), fmaxf(red[2], red[3]));
  am = fmaxf(am, 1e-12f);
  float sc = am / 448.0f;
  if (t == 0) xs[m] = sc;
  i32x4 out;
#pragma unroll
  for (int i = 0; i < 4; ++i) {
    float q0 = v[i][0] / sc, q1 = v[i][1] / sc;
    float q2 = v[i][2] / sc, q3 = v[i][3] / sc;
    int p = __builtin_amdgcn_cvt_pk_fp8_f32(q0, q1, 0, false);
    p = __builtin_amdgcn_cvt_pk_fp8_f32(q2, q3, p, true);
    out[i] = p;
  }
  *(i32x4*)(x8 + (size_t)m * K + t * 16) = out;
}

// ---------------------------------------------------------------------------
// Kernel 2 (R1, proven): weight f32 (fp8-representable) -> fp8 bytes
// ---------------------------------------------------------------------------
__global__ __launch_bounds__(256) void quant_w_fp8_kernel(
    const float* __restrict__ w, unsigned char* __restrict__ w8) {
  size_t idx = (size_t)blockIdx.x * 256 + threadIdx.x;
  const f32x4* src = (const f32x4*)w + idx * 4;
  i32x4 out;
#pragma unroll
  for (int i = 0; i < 4; ++i) {
    f32x4 v = src[i];
    int p = __builtin_amdgcn_cvt_pk_fp8_f32(v[0], v[1], 0, false);
    p = __builtin_amdgcn_cvt_pk_fp8_f32(v[2], v[3], p, true);
    out[i] = p;
  }
  ((i32x4*)w8)[idx] = out;
}

// ---------------------------------------------------------------------------
// Kernel 3: MX-fp8 GEMM. R28 = R27 (128x64 wave tile, 2 blocks/CU) +
// COUNTED vmcnt via A-triple/B-double buffering at exactly 65536 LDS.
// R27 post-mortem: best yet (GEMM 159.5us, FETCH halved to 148MB, 2
// blocks/CU confirmed by VGPR 120 + LDS 49152), but cycle audit: per 2
// block-bodies ~2980cy = LDS-port 1540 + MFMA 1100 summed SERIALLY --
// the per-body vmcnt(0) drain re-syncs both blocks to staging latency
// every body (m218: drain-0 pipeline ~= no pipeline; counted vmcnt =
// +38-73% there). R17/R20 had counted vmcnt at 1 block/CU; R27 has 2
// blocks with drain-0. R28 = both: LDS = A x3 (16KB) + B x2 (8KB) =
// 65536 exactly -- the size R23 PROVED co-resides 2 blocks/CU.
// Body T (K-64, R25/R27-validated layout/anchors/staging/fold):
//   read bufA(T%3), bufB(T%2); stage B(T+1)->bufB((T+1)%2) then
//   A(T+2)->bufA((T+2)%3); MFMA; vmcnt(4); barrier.
// Ledger: end-of-T queue = [A(T+1):4, B(T+1):2, A(T+2):4]; vmcnt(4)
// retires A(T+1)+B(T+1) (needed next body), leaves A(T+2) in flight
// ACROSS the barrier -- never drains in the main loop. Cover: B ~1 body
// (~1300cy > 900 HBM), A ~2 bodies. WAR: stage targets are the bufs last
// read in body T-1, >=1 closing barrier before issue (R17 rule). Static
// buf assignment via 6-body groups (lcm(3,2)); bodies 0..59 in loop,
// explicit tail 60..63 (vmcnt(0) only at bodies 62/63).
// Prologue: A(0),B(0),A(1) staged (10 gloads); vmcnt(4) retires A0+B0,
// leaves A(1):4 = steady entry invariant.
// launch_bounds(256,2): VGPR cap 256 >= R27's measured 120.
// Tripwires: Occupancy ~20-25 (11 => no co-residency, revert to R27);
// LDS_Block 65536; WRITE == 131072KB (else spill); VGPR 120-145.
// ---------------------------------------------------------------------------
__global__ __launch_bounds__(256, 2) void gemm_mxfp8_kernel(
    const unsigned char* __restrict__ A8,   // [M][K] fp8
    const unsigned char* __restrict__ W8,   // [N][K] fp8
    const float* __restrict__ xs,           // [M]
    const float* __restrict__ wsinv,        // [N/128][K/128]
    float* __restrict__ Y,                  // [M][N] f32
    int M, int N, int K) {
  const int KB = K >> 7;  // K/128 scale tiles (32); bodies = 64

  int bid = blockIdx.x, nwg = gridDim.x;
  int wg = (bid & 7) * (nwg >> 3) + (bid >> 3);
  int mt = M >> 8;                  // 16
  int bm = wg & (mt - 1);
  int bn = wg / mt;                 // 0..63
  int m0 = bm << 8, n0 = bn << 7;   // 256 x 128 tile

  // A bufs @0,@16384,@32768 (16KB); B bufs @49152,@57344 (8KB) = 65536
  __shared__ __align__(16) char lds[65536];

  const int tid = threadIdx.x, wv = tid >> 6, lane = tid & 63;
  const int wr = wv >> 1, wc = wv & 1;          // 2 x 2 wave grid
  const int l31 = lane & 31, hi2 = lane >> 5;

  // read anchors for the K-64 interleaved layout (R25/R27-validated):
  // anchor(s) = (l31>>1)*128 + ((((l31&1)<<2)|s) ^ ((l31>>1)&7))*16
  const int lineB = (l31 >> 1) * 128;
  const int par4 = (l31 & 1) << 2;
  const int xr = (l31 >> 1) & 7;
  const int s0 = 2 * hi2, s1 = 2 * hi2 + 1;
  const int aL = wr * 8192 + lineB + ((par4 | s0) ^ xr) * 16;
  const int aH = wr * 8192 + lineB + ((par4 | s1) ^ xr) * 16;
  const int bL = wc * 4096 + lineB + ((par4 | s0) ^ xr) * 16;
  const int bH = wc * 4096 + lineB + ((par4 | s1) ^ xr) * 16;

  // staging (R25/R27-validated): dest = buf + sweep*4096 + tid*16 (linear);
  // src row = 64*sweep + 2*(tid>>3) + (inv>>2), col = (inv&3)*16.
  const int stgD = tid << 4;
  const int inv = (tid & 7) ^ ((tid >> 3) & 7);
  const int rLoc = 2 * (tid >> 3) + (inv >> 2);
  const int cSrc = (inv & 3) << 4;
  const size_t rowB = (size_t)K;  // fp8: 1 byte/elem
  const size_t g64r = 64 * rowB;  // 64-row sweep stride
  const char* pA = (const char*)A8 + (size_t)(m0 + rLoc) * rowB + cSrc;
  const char* pB = (const char*)W8 + (size_t)(n0 + rLoc) * rowB + cSrc;

  const float* wsv = wsinv + (size_t)bn * KB;  // N-tile 128 = one scale row

  f32x16 acc[4][2];
#pragma unroll
  for (int i = 0; i < 4; ++i)
#pragma unroll
    for (int j = 0; j < 2; ++j) acc[i][j] = (f32x16)0.0f;

  i32x8 af, bf[2];

#define GL(SRC, DST)                                                           \
  __builtin_amdgcn_global_load_lds((const AS1 void*)(SRC), (AS3 void*)(DST),   \
                                   16, 0, 0)
// A panel (256 rows x 64B = 16KB): 4 sweeps
#define STG_A(COND, SB, SRC)                                                   \
  if (COND) {                                                                  \
    const char* s_ = (SRC);                                                    \
    char* d_ = lds + (SB) + stgD;                                              \
    GL(s_, d_);                                                                \
    GL(s_ + g64r, d_ + 4096);                                                  \
    GL(s_ + 2 * g64r, d_ + 8192);                                              \
    GL(s_ + 3 * g64r, d_ + 12288);                                             \
  }
// B panel (128 rows x 64B = 8KB): 2 sweeps (absolute base)
#define STG_B(COND, SB, SRC)                                                   \
  if (COND) {                                                                  \
    const char* s_ = (SRC);                                                    \
    char* d_ = lds + (SB) + stgD;                                              \
    GL(s_, d_);                                                                \
    GL(s_ + g64r, d_ + 4096);                                                  \
  }

// A frag for one mj (K-64), literal buf base RB: 2 ds_read_b128 -> af
#define RD_A(RB, MJ)                                                           \
  {                                                                            \
    const char* p_ = lds + (RB) + (MJ) * 2048;                                 \
    i32x4 lo = *(const i32x4*)(p_ + aL);                                       \
    i32x4 hi = *(const i32x4*)(p_ + aH);                                       \
    af = __builtin_shufflevector(lo, hi, 0, 1, 2, 3, 4, 5, 6, 7);              \
  }
// B frag for one nj (K-64), literal buf base RB (absolute)
#define RD_B(RB, NJ)                                                           \
  {                                                                            \
    const char* p_ = lds + (RB) + (NJ) * 2048;                                 \
    i32x4 lo = *(const i32x4*)(p_ + bL);                                       \
    i32x4 hi = *(const i32x4*)(p_ + bH);                                       \
    bf[NJ] = __builtin_shufflevector(lo, hi, 0, 1, 2, 3, 4, 5, 6, 7);          \
  }

// fold + MFMA (even bodies): acc = mfma(af, bf, acc*r)
#define MMFF(MJ, NJ, R_)                                                       \
  {                                                                            \
    _Pragma("unroll") for (int q = 0; q < 16; ++q)                             \
        acc[MJ][NJ][q] *= (R_);                                                \
    acc[MJ][NJ] = __builtin_amdgcn_mfma_scale_f32_32x32x64_f8f6f4(             \
        af, bf[NJ], acc[MJ][NJ], 0, 0, 0, 0x7f7f7f7f, 0, 0x7f7f7f7f);          \
  }
// direct MFMA (odd bodies): acc = mfma(af, bf, acc)
#define MMFD(MJ, NJ)                                                           \
  acc[MJ][NJ] = __builtin_amdgcn_mfma_scale_f32_32x32x64_f8f6f4(               \
      af, bf[NJ], acc[MJ][NJ], 0, 0, 0, 0x7f7f7f7f, 0, 0x7f7f7f7f);

// body: read from (AR, BR); stage B(T+1)->BS then A(T+2)->AS at top;
// MFMA; counted vmcnt; barrier.
#define BODY_CORE(MM0, MM1, MM2, MM3, AR, BR, BS, AS, GB, GA, VM)              \
  {                                                                            \
    RD_B(BR, 0);                                                               \
    RD_B(BR, 1);                                                               \
    RD_A(AR, 0);                                                               \
    STG_B(GB, BS, pBs);                                                        \
    STG_A(GA, AS, pAs);                                                        \
    __builtin_amdgcn_s_setprio(1);                                             \
    MM0;                                                                       \
    __builtin_amdgcn_s_setprio(0);                                             \
    RD_A(AR, 1);                                                               \
    __builtin_amdgcn_s_setprio(1);                                             \
    MM1;                                                                       \
    __builtin_amdgcn_s_setprio(0);                                             \
    RD_A(AR, 2);                                                               \
    __builtin_amdgcn_s_setprio(1);                                             \
    MM2;                                                                       \
    __builtin_amdgcn_s_setprio(0);                                             \
    RD_A(AR, 3);                                                               \
    __builtin_amdgcn_s_setprio(1);                                             \
    MM3;                                                                       \
    __builtin_amdgcn_s_setprio(0);                                             \
    asm volatile("s_waitcnt " VM ::: "memory");                                \
    __builtin_amdgcn_s_barrier();                                              \
    pAs += 64;                                                                 \
    pBs += 64;                                                                 \
  }

#define BODY_E(SC_, AR, BR, BS, AS, GB, GA, VM)                                \
  {                                                                            \
    float sc_ = (SC_);                                                         \
    float r_ = sp_ / sc_;                                                      \
    sp_ = sc_;                                                                 \
    BODY_CORE(MMFF(0, 0, r_); MMFF(0, 1, r_), MMFF(1, 0, r_); MMFF(1, 1, r_),  \
              MMFF(2, 0, r_); MMFF(2, 1, r_), MMFF(3, 0, r_); MMFF(3, 1, r_),  \
              AR, BR, BS, AS, GB, GA, VM)                                      \
  }
#define BODY_O(AR, BR, BS, AS, GB, GA, VM)                                     \
  BODY_CORE(MMFD(0, 0); MMFD(0, 1), MMFD(1, 0); MMFD(1, 1),                    \
            MMFD(2, 0); MMFD(2, 1), MMFD(3, 0); MMFD(3, 1),                    \
            AR, BR, BS, AS, GB, GA, VM)

  // prologue: A(0)->A0, B(0)->B0, A(1)->A1 (10 gloads); vmcnt(4) retires
  // A0+B0, leaves A(1):4 = steady entry invariant; barrier publishes.
  STG_A(true, 0, pA);
  STG_B(true, 49152, pB);
  STG_A(true, 16384, pA + 64);
  asm volatile("s_waitcnt vmcnt(4)" ::: "memory");
  __builtin_amdgcn_s_barrier();

  const char* pAs = pA + 128;  // A stage source (body T stages A(T+2))
  const char* pBs = pB + 64;   // B stage source (body T stages B(T+1))
  float sp_ = wsv[0];          // previous-tile scale (ratio = 1 at t = 0)

  // 6-body groups (bufA period 3 x bufB period 2), bodies 0..59;
  // body b: reads A(b%3), B(b%2); stages B->B((b+1)%2), A->A((b+2)%3).
#pragma unroll 1
  for (int t0 = 0; t0 < 30; t0 += 3) {
    float sA_ = wsv[t0], sB_ = wsv[t0 + 1], sC_ = wsv[t0 + 2];
    BODY_E(sA_, 0,     49152, 57344, 32768, true, true, "vmcnt(4)")
    BODY_O(     16384, 57344, 49152, 0,     true, true, "vmcnt(4)")
    BODY_E(sB_, 32768, 49152, 57344, 16384, true, true, "vmcnt(4)")
    BODY_O(     0,     57344, 49152, 32768, true, true, "vmcnt(4)")
    BODY_E(sC_, 16384, 49152, 57344, 0,     true, true, "vmcnt(4)")
    BODY_O(     32768, 57344, 49152, 16384, true, true, "vmcnt(4)")
  }
  // tail: bodies 60..63 (scale tiles 30, 31)
  BODY_E(wsv[30], 0,     49152, 57344, 32768, true,  true,  "vmcnt(4)")
  BODY_O(         16384, 57344, 49152, 0,     true,  true,  "vmcnt(4)")
  BODY_E(wsv[31], 32768, 49152, 57344, 0,     true,  false, "vmcnt(0)")
  BODY_O(         0,     57344, 49152, 0,     false, false, "vmcnt(0)")

#undef BODY_O
#undef BODY_E
#undef BODY_CORE
#undef MMFD
#undef MMFF
#undef RD_B
#undef RD_A
#undef STG_B
#undef STG_A
#undef GL

  // epilogue (R24/R25/R27-proven mapping, wave 128x64): col=l31,
  // row=q*8+hi2*4+j. acc is in s_last domain: Y = acc * s_last * xs[row].
  const float sl_ = sp_;
#pragma unroll
  for (int mj = 0; mj < 4; ++mj)
#pragma unroll
    for (int nj = 0; nj < 2; ++nj) {
      int col = n0 + wc * 64 + nj * 32 + l31;
#pragma unroll
      for (int q = 0; q < 4; ++q) {
        int row0 = m0 + wr * 128 + mj * 32 + q * 8 + hi2 * 4;
        f32x4 sv = *(const f32x4*)(xs + row0);
#pragma unroll
        for (int j = 0; j < 4; ++j)
          Y[(size_t)(row0 + j) * N + col] = acc[mj][nj][q * 4 + j] * sv[j] * sl_;
      }
    }
}

// ---------------------------------------------------------------------------
extern "C" void kernel_launch(void* const* d_in, const int* in_sizes, int n_in,
                              void* d_out, int out_size, void* d_ws, size_t ws_size,
                              hipStream_t stream) {
  const float* x     = (const float*)d_in[0];   // [B,S,K] f32
  const float* w     = (const float*)d_in[1];   // [N,K] f32 (fp8-representable)
  const float* wsinv = (const float*)d_in[2];   // [N/128,K/128] f32
  float* y = (float*)d_out;

  const int K = 4096;
  const int M = in_sizes[0] / K;   // 4096
  const int N = in_sizes[1] / K;   // 8192

  unsigned char* x8 = (unsigned char*)d_ws;                       // M*K
  float* xs = (float*)((char*)d_ws + (size_t)M * K);              // M floats
  unsigned char* w8 =
      (unsigned char*)d_ws + (size_t)M * K + (size_t)M * 4;       // N*K

  quant_x_fp8_kernel<<<M, 256, 0, stream>>>(x, x8, xs, K);
  quant_w_fp8_kernel<<<(int)(((size_t)N * K / 16 + 255) / 256), 256, 0,
                       stream>>>(w, w8);

  dim3 grid((M / 256) * (N / 128));  // 1024
  gemm_mxfp8_kernel<<<grid, 256, 0, stream>>>(x8, w8, xs, wsinv, y, M, N, K);
}